// Round 1
// 479.169 us; speedup vs baseline: 1.3216x; 1.3216x over previous
//
#include <hip/hip_runtime.h>
#include <hip/hip_bf16.h>

typedef __hip_bfloat16 bf16;

constexpr int kB  = 2;
constexpr int kC  = 64;
constexpr int kCi = 16;
constexpr int kN  = 6400;   // 80*80
constexpr int QT  = 16;     // queries per block
constexpr int KT  = 128;    // keys per LDS chunk
#define EPS_BN 1e-5f

__device__ __forceinline__ float b2f(bf16 v) { return __bfloat162float(v); }

// Dynamic-dtype input load / output store (flag: 1 = bf16, 0 = fp32)
__device__ __forceinline__ float ldin(const void* p, size_t i, int bf) {
    return bf ? __bfloat162float(((const bf16*)p)[i]) : ((const float*)p)[i];
}
__device__ __forceinline__ void stout(void* p, size_t i, float v, int bf) {
    if (bf) ((bf16*)p)[i] = __float2bfloat16(v);
    else    ((float*)p)[i] = v;
}

// ---------------------------------------------------------------------------
// Kernel 0: dtype detector (unchanged).
// ---------------------------------------------------------------------------
__global__ __launch_bounds__(256)
void detect_kernel(const void* __restrict__ src, int* __restrict__ flag)
{
    __shared__ int cnt[256];
    const unsigned short* u = (const unsigned short*)src;
    int wild = 0;
    for (int i = threadIdx.x; i < 8192; i += 256) {
        int e = (u[i] >> 7) & 0xFF;
        if (e < 64 || e > 191) wild++;
    }
    cnt[threadIdx.x] = wild;
    __syncthreads();
    for (int s = 128; s > 0; s >>= 1) {
        if (threadIdx.x < s) cnt[threadIdx.x] += cnt[threadIdx.x + s];
        __syncthreads();
    }
    if (threadIdx.x == 0) *flag = (cnt[0] * 8 < 8192) ? 1 : 0;
}

// ---------------------------------------------------------------------------
// Kernel 1: four 1x1-conv projections -> fp32 proj[k][b][ci][n] (unchanged).
// ---------------------------------------------------------------------------
__global__ __launch_bounds__(256)
void proj_kernel(const void* __restrict__ bfimg, const void* __restrict__ x,
                 const void* __restrict__ w_theta, const void* __restrict__ b_theta,
                 const void* __restrict__ w_phi,   const void* __restrict__ b_phi,
                 const void* __restrict__ w_g,     const void* __restrict__ b_g,
                 const void* __restrict__ w_gbf,   const void* __restrict__ b_gbf,
                 const int* __restrict__ flagp, float* __restrict__ proj)
{
    const int bf = *flagp;
    int idx = blockIdx.x * 256 + threadIdx.x;
    int n = idx % kN;
    int t = idx / kN;
    int c = t % kCi; t /= kCi;
    int b = t % kB;
    int k = t / kB;

    const void *src, *w, *bias;
    if (k == 0)      { src = bfimg; w = w_theta; bias = b_theta; }
    else if (k == 1) { src = bfimg; w = w_phi;   bias = b_phi;   }
    else if (k == 2) { src = x;     w = w_g;     bias = b_g;     }
    else             { src = bfimg; w = w_gbf;   bias = b_gbf;   }

    size_t sbase = (size_t)b * kC * kN + n;
    float acc;
    if (bf) {
        const bf16* sp = (const bf16*)src + sbase;
        const bf16* wp = (const bf16*)w + c * kC;
        acc = b2f(((const bf16*)bias)[c]);
#pragma unroll 8
        for (int ch = 0; ch < kC; ++ch)
            acc = fmaf(b2f(wp[ch]), b2f(sp[(size_t)ch * kN]), acc);
    } else {
        const float* sp = (const float*)src + sbase;
        const float* wp = (const float*)w + c * kC;
        acc = ((const float*)bias)[c];
#pragma unroll 8
        for (int ch = 0; ch < kC; ++ch)
            acc = fmaf(wp[ch], sp[(size_t)ch * kN], acc);
    }
    proj[idx] = acc;
}

// ---------------------------------------------------------------------------
// Kernel 2: query-tiled streaming attention.
//   Block = 16 queries (8 qgroups x 2 q/thread) x 32 key-threads.
//   Keys streamed through LDS in 128-wide chunks (float4-staged).
//   No max-subtraction: scores ~N(0,0.64^2), max ~4, exp() safe in fp32 and
//   mathematically identical to softmax-with-max. Per-thread partial (l, acc)
//   over its key subset; exact merge via shfl_xor butterfly.
//   Epilogue: w_W (pre-scaled by BN) + shift + residual, fused.
// ---------------------------------------------------------------------------
__global__ __launch_bounds__(256, 2)
void attn_kernel(const float* __restrict__ proj,
                 const void* __restrict__ bfimg, const void* __restrict__ x,
                 const void* __restrict__ w_W,  const void* __restrict__ b_W,
                 const void* __restrict__ gamma, const void* __restrict__ beta,
                 const void* __restrict__ mean,  const void* __restrict__ var,
                 const int* __restrict__ flagp, void* __restrict__ out)
{
    __shared__ float ph_s[kCi][KT];        // 8 KB
    __shared__ float gx_s[kCi][KT];        // 8 KB
    __shared__ float gb_s[kCi][KT];        // 8 KB
    __shared__ float th_s[kCi][QT];        // 1 KB
    __shared__ float w_sT[kCi][kC];        // 4 KB, BN-prescaled, ci-major
    __shared__ float sBs[kC];              // BN shift incl. b_W
    __shared__ float y_s[QT][2 * kCi + 1]; // padded (+1) for bank-free reads

    const int bf  = *flagp;
    const int tid = threadIdx.x;
    const int b   = blockIdx.x / (kN / QT);
    const int q0  = (blockIdx.x % (kN / QT)) * QT;
    const int qg  = tid >> 5;              // 0..7 query group
    const int kt  = tid & 31;              // 0..31 key-thread

    const float* theta = proj + (size_t)(0 * kB + b) * kCi * kN;
    const float* phi   = proj + (size_t)(1 * kB + b) * kCi * kN;
    const float* gx    = proj + (size_t)(2 * kB + b) * kCi * kN;
    const float* gbf   = proj + (size_t)(3 * kB + b) * kCi * kN;

    // ---- prologue staging ----
    {
        int c = tid >> 4, q = tid & 15;
        th_s[c][q] = theta[(size_t)c * kN + q0 + q];
    }
#pragma unroll
    for (int r = 0; r < 4; ++r) {          // 1024 w_W elements, BN-prescaled
        int idx = r * 256 + tid;
        int ci = idx >> 6, ch = idx & 63;
        float a = ldin(gamma, ch, bf) * rsqrtf(ldin(var, ch, bf) + EPS_BN);
        w_sT[ci][ch] = ldin(w_W, (size_t)ch * kCi + ci, bf) * a;
    }
    if (tid < kC) {
        float a = ldin(gamma, tid, bf) * rsqrtf(ldin(var, tid, bf) + EPS_BN);
        sBs[tid] = (ldin(b_W, tid, bf) - ldin(mean, tid, bf)) * a + ldin(beta, tid, bf);
    }
    __syncthreads();

    float th0[kCi], th1[kCi];
#pragma unroll
    for (int c = 0; c < kCi; ++c) {
        th0[c] = th_s[c][qg * 2 + 0];
        th1[c] = th_s[c][qg * 2 + 1];
    }

    // fixed per-thread staging coordinates (2 float4 rows per array)
    const int c0  = tid >> 5;            // 0..7
    const int c1  = c0 + 8;
    const int kof = (tid & 31) * 4;

    const float* pph0 = phi + (size_t)c0 * kN + kof;
    const float* pph1 = phi + (size_t)c1 * kN + kof;
    const float* pgx0 = gx  + (size_t)c0 * kN + kof;
    const float* pgx1 = gx  + (size_t)c1 * kN + kof;
    const float* pgb0 = gbf + (size_t)c0 * kN + kof;
    const float* pgb1 = gbf + (size_t)c1 * kN + kof;
    float* dph0 = &ph_s[c0][kof];
    float* dph1 = &ph_s[c1][kof];
    float* dgx0 = &gx_s[c0][kof];
    float* dgx1 = &gx_s[c1][kof];
    float* dgb0 = &gb_s[c0][kof];
    float* dgb1 = &gb_s[c1][kof];

    float accx0[kCi], accx1[kCi], accb0[kCi], accb1[kCi];
#pragma unroll
    for (int c = 0; c < kCi; ++c) accx0[c] = accx1[c] = accb0[c] = accb1[c] = 0.f;
    float l0 = 0.f, l1 = 0.f;

    for (int k0 = 0; k0 < kN; k0 += KT) {
        *(float4*)dph0 = *(const float4*)(pph0 + k0);
        *(float4*)dph1 = *(const float4*)(pph1 + k0);
        *(float4*)dgx0 = *(const float4*)(pgx0 + k0);
        *(float4*)dgx1 = *(const float4*)(pgx1 + k0);
        *(float4*)dgb0 = *(const float4*)(pgb0 + k0);
        *(float4*)dgb1 = *(const float4*)(pgb1 + k0);
        __syncthreads();

        // scores for 2 queries x 4 keys
        float s00 = 0.f, s01 = 0.f, s02 = 0.f, s03 = 0.f;
        float s10 = 0.f, s11 = 0.f, s12 = 0.f, s13 = 0.f;
#pragma unroll
        for (int c = 0; c < kCi; ++c) {
            const float4 ph = *(const float4*)&ph_s[c][kt * 4];
            s00 = fmaf(th0[c], ph.x, s00);
            s01 = fmaf(th0[c], ph.y, s01);
            s02 = fmaf(th0[c], ph.z, s02);
            s03 = fmaf(th0[c], ph.w, s03);
            s10 = fmaf(th1[c], ph.x, s10);
            s11 = fmaf(th1[c], ph.y, s11);
            s12 = fmaf(th1[c], ph.z, s12);
            s13 = fmaf(th1[c], ph.w, s13);
        }
        const float p00 = __expf(s00), p01 = __expf(s01);
        const float p02 = __expf(s02), p03 = __expf(s03);
        const float p10 = __expf(s10), p11 = __expf(s11);
        const float p12 = __expf(s12), p13 = __expf(s13);
        l0 += (p00 + p01) + (p02 + p03);
        l1 += (p10 + p11) + (p12 + p13);

        // dual-branch PV accumulate
#pragma unroll
        for (int c = 0; c < kCi; ++c) {
            const float4 g = *(const float4*)&gx_s[c][kt * 4];
            accx0[c] = fmaf(p00, g.x, fmaf(p01, g.y, fmaf(p02, g.z, fmaf(p03, g.w, accx0[c]))));
            accx1[c] = fmaf(p10, g.x, fmaf(p11, g.y, fmaf(p12, g.z, fmaf(p13, g.w, accx1[c]))));
            const float4 h = *(const float4*)&gb_s[c][kt * 4];
            accb0[c] = fmaf(p00, h.x, fmaf(p01, h.y, fmaf(p02, h.z, fmaf(p03, h.w, accb0[c]))));
            accb1[c] = fmaf(p10, h.x, fmaf(p11, h.y, fmaf(p12, h.z, fmaf(p13, h.w, accb1[c]))));
        }
        __syncthreads();
    }

    // ---- exact merge across the 32 key-threads of each query group ----
#pragma unroll
    for (int off = 1; off <= 16; off <<= 1) {
        l0 += __shfl_xor(l0, off);
        l1 += __shfl_xor(l1, off);
#pragma unroll
        for (int c = 0; c < kCi; ++c) {
            accx0[c] += __shfl_xor(accx0[c], off);
            accx1[c] += __shfl_xor(accx1[c], off);
            accb0[c] += __shfl_xor(accb0[c], off);
            accb1[c] += __shfl_xor(accb1[c], off);
        }
    }
    if (kt == 0) {
        const float il0 = 1.0f / l0, il1 = 1.0f / l1;
#pragma unroll
        for (int c = 0; c < kCi; ++c) {
            y_s[qg * 2 + 0][c]       = accx0[c] * il0;
            y_s[qg * 2 + 0][kCi + c] = accb0[c] * il0;
            y_s[qg * 2 + 1][c]       = accx1[c] * il1;
            y_s[qg * 2 + 1][kCi + c] = accb1[c] * il1;
        }
    }
    __syncthreads();

    // ---- epilogue: z = w_W'.y + shift + residual, both branches ----
    const int q  = tid & 15;
    const int cb = tid >> 4;             // 0..15
#pragma unroll
    for (int i = 0; i < 8; ++i) {
        const int ch2 = cb * 8 + i;      // 0..127
        const int br  = ch2 >> 6;        // 0: x-branch, 1: bfimg-branch
        const int ch  = ch2 & 63;
        float wy = sBs[ch];
#pragma unroll
        for (int ci = 0; ci < kCi; ++ci)
            wy = fmaf(w_sT[ci][ch], y_s[q][br * kCi + ci], wy);
        const void* res = br ? bfimg : x;
        wy += ldin(res, ((size_t)b * kC + ch) * kN + q0 + q, bf);
        stout(out, ((size_t)b * 2 * kC + ch2) * kN + q0 + q, wy, bf);
    }
}

// ---------------------------------------------------------------------------
extern "C" void kernel_launch(void* const* d_in, const int* in_sizes, int n_in,
                              void* d_out, int out_size, void* d_ws, size_t ws_size,
                              hipStream_t stream)
{
    const void* bfimg   = d_in[0];
    const void* x       = d_in[1];
    const void* w_theta = d_in[2];
    const void* b_theta = d_in[3];
    const void* w_phi   = d_in[4];
    const void* b_phi   = d_in[5];
    const void* w_g     = d_in[6];
    const void* b_g     = d_in[7];
    const void* w_gbf   = d_in[8];
    const void* b_gbf   = d_in[9];
    const void* w_W     = d_in[10];
    const void* b_W     = d_in[11];
    const void* gamma   = d_in[12];
    const void* beta    = d_in[13];
    const void* mean    = d_in[14];
    const void* var     = d_in[15];

    int*   flag = (int*)d_ws;                    // 4 B flag at offset 0
    float* proj = (float*)((char*)d_ws + 256);   // 4*kB*kCi*kN fp32 = 3.28 MB

    detect_kernel<<<1, 256, 0, stream>>>(bfimg, flag);

    proj_kernel<<<(4 * kB * kCi * kN) / 256, 256, 0, stream>>>(
        bfimg, x, w_theta, b_theta, w_phi, b_phi, w_g, b_g, w_gbf, b_gbf,
        flag, proj);

    attn_kernel<<<kB * (kN / QT), 256, 0, stream>>>(
        proj, bfimg, x, w_W, b_W, gamma, beta, mean, var, flag, d_out);
}

// Round 2
// 349.398 us; speedup vs baseline: 1.8125x; 1.3714x over previous
//
#include <hip/hip_runtime.h>
#include <hip/hip_bf16.h>

typedef __hip_bfloat16 bf16;

constexpr int kB  = 2;
constexpr int kC  = 64;
constexpr int kCi = 16;
constexpr int kN  = 6400;   // 80*80
constexpr int QT  = 16;     // queries per block
constexpr int KT  = 128;    // keys per LDS chunk
constexpr int NIT = kN / KT;
#define EPS_BN 1e-5f

__device__ __forceinline__ float b2f(bf16 v) { return __bfloat162float(v); }
__device__ __forceinline__ float us2f(unsigned short u) {
    return __uint_as_float(((unsigned)u) << 16);   // bf16 bits -> fp32, exact
}

// Dynamic-dtype input load / output store (flag: 1 = bf16, 0 = fp32)
__device__ __forceinline__ float ldin(const void* p, size_t i, int bf) {
    return bf ? __bfloat162float(((const bf16*)p)[i]) : ((const float*)p)[i];
}
__device__ __forceinline__ void stout(void* p, size_t i, float v, int bf) {
    if (bf) ((bf16*)p)[i] = __float2bfloat16(v);
    else    ((float*)p)[i] = v;
}

// 16B global -> LDS direct DMA (counts in vmcnt; __syncthreads drains it)
__device__ __forceinline__ void g2lds16(const float* gsrc, float* ldst) {
    __builtin_amdgcn_global_load_lds(
        (const __attribute__((address_space(1))) void*)gsrc,
        (__attribute__((address_space(3))) void*)ldst,
        16, 0, 0);
}

// ---------------------------------------------------------------------------
// Kernel 0: dtype detector (unchanged).
// ---------------------------------------------------------------------------
__global__ __launch_bounds__(256)
void detect_kernel(const void* __restrict__ src, int* __restrict__ flag)
{
    __shared__ int cnt[256];
    const unsigned short* u = (const unsigned short*)src;
    int wild = 0;
    for (int i = threadIdx.x; i < 8192; i += 256) {
        int e = (u[i] >> 7) & 0xFF;
        if (e < 64 || e > 191) wild++;
    }
    cnt[threadIdx.x] = wild;
    __syncthreads();
    for (int s = 128; s > 0; s >>= 1) {
        if (threadIdx.x < s) cnt[threadIdx.x] += cnt[threadIdx.x + s];
        __syncthreads();
    }
    if (threadIdx.x == 0) *flag = (cnt[0] * 8 < 8192) ? 1 : 0;
}

// ---------------------------------------------------------------------------
// Kernel 1: four 1x1-conv projections -> fp32 proj[k][b][ci][n].
// Vectorized x4 along n: ushort4 (bf16) / float4 (fp32) loads, float4 store.
// ---------------------------------------------------------------------------
__global__ __launch_bounds__(256)
void proj_kernel(const void* __restrict__ bfimg, const void* __restrict__ x,
                 const void* __restrict__ w_theta, const void* __restrict__ b_theta,
                 const void* __restrict__ w_phi,   const void* __restrict__ b_phi,
                 const void* __restrict__ w_g,     const void* __restrict__ b_g,
                 const void* __restrict__ w_gbf,   const void* __restrict__ b_gbf,
                 const int* __restrict__ flagp, float* __restrict__ proj)
{
    const int bf = *flagp;
    int idx = blockIdx.x * 256 + threadIdx.x;        // over 4*kB*kCi*(kN/4)
    int n = (idx % (kN / 4)) * 4;
    int t = idx / (kN / 4);
    int c = t % kCi; t /= kCi;
    int b = t % kB;
    int k = t / kB;

    const void *src, *w, *bias;
    if (k == 0)      { src = bfimg; w = w_theta; bias = b_theta; }
    else if (k == 1) { src = bfimg; w = w_phi;   bias = b_phi;   }
    else if (k == 2) { src = x;     w = w_g;     bias = b_g;     }
    else             { src = bfimg; w = w_gbf;   bias = b_gbf;   }

    size_t sbase = (size_t)b * kC * kN + n;
    float a0, a1, a2, a3;
    if (bf) {
        const unsigned short* sp = (const unsigned short*)src + sbase;
        const bf16* wp = (const bf16*)w + c * kC;
        float bv = b2f(((const bf16*)bias)[c]);
        a0 = a1 = a2 = a3 = bv;
#pragma unroll 8
        for (int ch = 0; ch < kC; ++ch) {
            float wv = b2f(wp[ch]);
            ushort4 v = *(const ushort4*)(sp + (size_t)ch * kN);
            a0 = fmaf(wv, us2f(v.x), a0);
            a1 = fmaf(wv, us2f(v.y), a1);
            a2 = fmaf(wv, us2f(v.z), a2);
            a3 = fmaf(wv, us2f(v.w), a3);
        }
    } else {
        const float* sp = (const float*)src + sbase;
        const float* wp = (const float*)w + c * kC;
        float bv = ((const float*)bias)[c];
        a0 = a1 = a2 = a3 = bv;
#pragma unroll 8
        for (int ch = 0; ch < kC; ++ch) {
            float wv = wp[ch];
            float4 v = *(const float4*)(sp + (size_t)ch * kN);
            a0 = fmaf(wv, v.x, a0);
            a1 = fmaf(wv, v.y, a1);
            a2 = fmaf(wv, v.z, a2);
            a3 = fmaf(wv, v.w, a3);
        }
    }
    float4 r; r.x = a0; r.y = a1; r.z = a2; r.w = a3;
    *(float4*)&proj[((size_t)(k * kB + b) * kCi + c) * kN + n] = r;
}

// ---------------------------------------------------------------------------
// Kernel 2: query-tiled streaming attention, double-buffered via
// global_load_lds (direct-to-LDS DMA). One __syncthreads per key chunk; its
// implicit vmcnt(0) drain doubles as the next-buffer readiness wait, so the
// L2 latency of chunk k+1's staging hides under chunk k's compute.
// Math identical to round-1 version (fp32, exact softmax, no max-sub).
// ---------------------------------------------------------------------------
__global__ __launch_bounds__(256, 2)
void attn_kernel(const float* __restrict__ proj,
                 const void* __restrict__ bfimg, const void* __restrict__ x,
                 const void* __restrict__ w_W,  const void* __restrict__ b_W,
                 const void* __restrict__ gamma, const void* __restrict__ beta,
                 const void* __restrict__ mean,  const void* __restrict__ var,
                 const int* __restrict__ flagp, void* __restrict__ out)
{
    __shared__ float ph_s[2][kCi][KT];     // 16 KB
    __shared__ float gx_s[2][kCi][KT];     // 16 KB
    __shared__ float gb_s[2][kCi][KT];     // 16 KB
    __shared__ float th_s[kCi][QT];        // 1 KB
    __shared__ float y_s[QT][2 * kCi + 1]; // 2.1 KB, padded

    const int bf  = *flagp;
    const int tid = threadIdx.x;
    const int b   = blockIdx.x / (kN / QT);
    const int q0  = (blockIdx.x % (kN / QT)) * QT;
    const int qg  = tid >> 5;              // 0..7 query group
    const int kt  = tid & 31;              // 0..31 key-thread

    const float* theta = proj + (size_t)(0 * kB + b) * kCi * kN;
    const float* phi   = proj + (size_t)(1 * kB + b) * kCi * kN;
    const float* gx    = proj + (size_t)(2 * kB + b) * kCi * kN;
    const float* gbf   = proj + (size_t)(3 * kB + b) * kCi * kN;

    // fixed per-thread staging coordinates: 2 rows (c0, c0+8), 16B each.
    // Wave-linear LDS dest: lane l of wave w writes base + w*1024 + l*16.
    const int c0  = tid >> 5;              // 0..7
    const int off0 = c0 * KT + (tid & 31) * 4;
    const int off1 = (c0 + 8) * KT + (tid & 31) * 4;

    const float* pph0 = phi + (size_t)c0 * kN + (tid & 31) * 4;
    const float* pph1 = phi + (size_t)(c0 + 8) * kN + (tid & 31) * 4;
    const float* pgx0 = gx  + (size_t)c0 * kN + (tid & 31) * 4;
    const float* pgx1 = gx  + (size_t)(c0 + 8) * kN + (tid & 31) * 4;
    const float* pgb0 = gbf + (size_t)c0 * kN + (tid & 31) * 4;
    const float* pgb1 = gbf + (size_t)(c0 + 8) * kN + (tid & 31) * 4;

#define STAGE(buf, k0)                                          \
    do {                                                        \
        float* bp = &ph_s[buf][0][0];                           \
        float* bx = &gx_s[buf][0][0];                           \
        float* bb = &gb_s[buf][0][0];                           \
        g2lds16(pph0 + (k0), bp + off0);                        \
        g2lds16(pph1 + (k0), bp + off1);                        \
        g2lds16(pgx0 + (k0), bx + off0);                        \
        g2lds16(pgx1 + (k0), bx + off1);                        \
        g2lds16(pgb0 + (k0), bb + off0);                        \
        g2lds16(pgb1 + (k0), bb + off1);                        \
    } while (0)

    // ---- prologue: stage chunk 0 + theta tile ----
    STAGE(0, 0);
    {
        int c = tid >> 4, q = tid & 15;
        th_s[c][q] = theta[(size_t)c * kN + q0 + q];
    }
    __syncthreads();                        // chunk 0 + th_s ready

    float th0[kCi], th1[kCi];
#pragma unroll
    for (int c = 0; c < kCi; ++c) {
        th0[c] = th_s[c][qg * 2 + 0];
        th1[c] = th_s[c][qg * 2 + 1];
    }

    float accx0[kCi], accx1[kCi], accb0[kCi], accb1[kCi];
#pragma unroll
    for (int c = 0; c < kCi; ++c) accx0[c] = accx1[c] = accb0[c] = accb1[c] = 0.f;
    float l0 = 0.f, l1 = 0.f;

    int cur = 0;
    for (int it = 0; it < NIT; ++it) {
        if (it + 1 < NIT) STAGE(cur ^ 1, (it + 1) * KT);

        // scores for 2 queries x 4 keys
        float s00 = 0.f, s01 = 0.f, s02 = 0.f, s03 = 0.f;
        float s10 = 0.f, s11 = 0.f, s12 = 0.f, s13 = 0.f;
#pragma unroll
        for (int c = 0; c < kCi; ++c) {
            const float4 ph = *(const float4*)&ph_s[cur][c][kt * 4];
            s00 = fmaf(th0[c], ph.x, s00);
            s01 = fmaf(th0[c], ph.y, s01);
            s02 = fmaf(th0[c], ph.z, s02);
            s03 = fmaf(th0[c], ph.w, s03);
            s10 = fmaf(th1[c], ph.x, s10);
            s11 = fmaf(th1[c], ph.y, s11);
            s12 = fmaf(th1[c], ph.z, s12);
            s13 = fmaf(th1[c], ph.w, s13);
        }
        const float p00 = __expf(s00), p01 = __expf(s01);
        const float p02 = __expf(s02), p03 = __expf(s03);
        const float p10 = __expf(s10), p11 = __expf(s11);
        const float p12 = __expf(s12), p13 = __expf(s13);
        l0 += (p00 + p01) + (p02 + p03);
        l1 += (p10 + p11) + (p12 + p13);

        // dual-branch PV accumulate
#pragma unroll
        for (int c = 0; c < kCi; ++c) {
            const float4 g = *(const float4*)&gx_s[cur][c][kt * 4];
            accx0[c] = fmaf(p00, g.x, fmaf(p01, g.y, fmaf(p02, g.z, fmaf(p03, g.w, accx0[c]))));
            accx1[c] = fmaf(p10, g.x, fmaf(p11, g.y, fmaf(p12, g.z, fmaf(p13, g.w, accx1[c]))));
            const float4 h = *(const float4*)&gb_s[cur][c][kt * 4];
            accb0[c] = fmaf(p00, h.x, fmaf(p01, h.y, fmaf(p02, h.z, fmaf(p03, h.w, accb0[c]))));
            accb1[c] = fmaf(p10, h.x, fmaf(p11, h.y, fmaf(p12, h.z, fmaf(p13, h.w, accb1[c]))));
        }

        __syncthreads();   // drains vmcnt(0): next buffer staged; all reads of cur done
        cur ^= 1;
    }
#undef STAGE

    // ---- exact merge across the 32 key-threads of each query group ----
#pragma unroll
    for (int off = 1; off <= 16; off <<= 1) {
        l0 += __shfl_xor(l0, off);
        l1 += __shfl_xor(l1, off);
#pragma unroll
        for (int c = 0; c < kCi; ++c) {
            accx0[c] += __shfl_xor(accx0[c], off);
            accx1[c] += __shfl_xor(accx1[c], off);
            accb0[c] += __shfl_xor(accb0[c], off);
            accb1[c] += __shfl_xor(accb1[c], off);
        }
    }
    if (kt == 0) {
        const float il0 = 1.0f / l0, il1 = 1.0f / l1;
#pragma unroll
        for (int c = 0; c < kCi; ++c) {
            y_s[qg * 2 + 0][c]       = accx0[c] * il0;
            y_s[qg * 2 + 0][kCi + c] = accb0[c] * il0;
            y_s[qg * 2 + 1][c]       = accx1[c] * il1;
            y_s[qg * 2 + 1][kCi + c] = accb1[c] * il1;
        }
    }
    __syncthreads();

    // ---- epilogue: z = BN(w_W . y + b_W) + residual, both branches ----
    const int q  = tid & 15;
    const int cb = tid >> 4;             // 0..15
#pragma unroll
    for (int i = 0; i < 8; ++i) {
        const int ch2 = cb * 8 + i;      // 0..127
        const int br  = ch2 >> 6;        // 0: x-branch, 1: bfimg-branch
        const int ch  = ch2 & 63;
        float wy = ldin(b_W, ch, bf);
#pragma unroll
        for (int ci = 0; ci < kCi; ++ci)
            wy = fmaf(ldin(w_W, (size_t)ch * kCi + ci, bf), y_s[q][br * kCi + ci], wy);
        float inv = rsqrtf(ldin(var, ch, bf) + EPS_BN);
        float z = (wy - ldin(mean, ch, bf)) * (ldin(gamma, ch, bf) * inv) + ldin(beta, ch, bf);
        const void* res = br ? bfimg : x;
        z += ldin(res, ((size_t)b * kC + ch) * kN + q0 + q, bf);
        stout(out, ((size_t)b * 2 * kC + ch2) * kN + q0 + q, z, bf);
    }
}

// ---------------------------------------------------------------------------
extern "C" void kernel_launch(void* const* d_in, const int* in_sizes, int n_in,
                              void* d_out, int out_size, void* d_ws, size_t ws_size,
                              hipStream_t stream)
{
    const void* bfimg   = d_in[0];
    const void* x       = d_in[1];
    const void* w_theta = d_in[2];
    const void* b_theta = d_in[3];
    const void* w_phi   = d_in[4];
    const void* b_phi   = d_in[5];
    const void* w_g     = d_in[6];
    const void* b_g     = d_in[7];
    const void* w_gbf   = d_in[8];
    const void* b_gbf   = d_in[9];
    const void* w_W     = d_in[10];
    const void* b_W     = d_in[11];
    const void* gamma   = d_in[12];
    const void* beta    = d_in[13];
    const void* mean    = d_in[14];
    const void* var     = d_in[15];

    int*   flag = (int*)d_ws;                    // 4 B flag at offset 0
    float* proj = (float*)((char*)d_ws + 256);   // 4*kB*kCi*kN fp32 = 3.28 MB

    detect_kernel<<<1, 256, 0, stream>>>(bfimg, flag);

    proj_kernel<<<(4 * kB * kCi * (kN / 4)) / 256, 256, 0, stream>>>(
        bfimg, x, w_theta, b_theta, w_phi, b_phi, w_g, b_g, w_gbf, b_gbf,
        flag, proj);

    attn_kernel<<<kB * (kN / QT), 256, 0, stream>>>(
        proj, bfimg, x, w_W, b_W, gamma, beta, mean, var, flag, d_out);
}

// Round 3
// 201.116 us; speedup vs baseline: 3.1488x; 1.7373x over previous
//
#include <hip/hip_runtime.h>
#include <hip/hip_bf16.h>

typedef __hip_bfloat16 bf16;
typedef __attribute__((ext_vector_type(4))) float f32x4;
typedef __attribute__((ext_vector_type(8))) short bf16x8;

constexpr int kB  = 2;
constexpr int kC  = 64;
constexpr int kCi = 16;
constexpr int kN  = 6400;   // 80*80
constexpr int QT  = 16;     // queries per block
constexpr int KT  = 128;    // keys per chunk
constexpr int NCH = kN / KT; // 50

// proj scratch layouts (all bf16):
//   theta: [b][n][ci]              rows 32 B
//   phi:   [b][n][ci + 8B pad]     rows 48 B (pad unread; keeps b128 rows 16B-aligned, 2-way banks)
//   gx/gb: [b][n/4][ci][4keys]+pad groups 160 B (128 used)
constexpr int THB = 32;
constexpr int PHB = 48;
constexpr int GRB = 160;
constexpr int PH_BYTES  = KT * PHB;        // 6144
constexpr int G_BYTES   = (KT / 4) * GRB;  // 5120
constexpr int BUF_BYTES = PH_BYTES + 2 * G_BYTES; // 16384 (ph | gx | gb contiguous)

#define EPS_BN 1e-5f

__device__ __forceinline__ float b2f(bf16 v) { return __bfloat162float(v); }
__device__ __forceinline__ unsigned short f2bf(float f) {
    bf16 h = __float2bfloat16(f);
    return *reinterpret_cast<unsigned short*>(&h);
}
__device__ __forceinline__ float ldin(const void* p, size_t i, int bf) {
    return bf ? __bfloat162float(((const bf16*)p)[i]) : ((const float*)p)[i];
}
__device__ __forceinline__ void stout(void* p, size_t i, float v, int bf) {
    if (bf) ((bf16*)p)[i] = __float2bfloat16(v);
    else    ((float*)p)[i] = v;
}
__device__ __forceinline__ void g2lds16(const void* gsrc, void* ldst) {
    __builtin_amdgcn_global_load_lds(
        (const __attribute__((address_space(1))) void*)gsrc,
        (__attribute__((address_space(3))) void*)ldst,
        16, 0, 0);
}
__device__ __forceinline__ unsigned pack2(unsigned short a, unsigned short b) {
    return (unsigned)a | ((unsigned)b << 16);
}

// ---------------------------------------------------------------------------
// Kernel 0: dtype detector (unchanged).
// ---------------------------------------------------------------------------
__global__ __launch_bounds__(256)
void detect_kernel(const void* __restrict__ src, int* __restrict__ flag)
{
    __shared__ int cnt[256];
    const unsigned short* u = (const unsigned short*)src;
    int wild = 0;
    for (int i = threadIdx.x; i < 8192; i += 256) {
        int e = (u[i] >> 7) & 0xFF;
        if (e < 64 || e > 191) wild++;
    }
    cnt[threadIdx.x] = wild;
    __syncthreads();
    for (int s = 128; s > 0; s >>= 1) {
        if (threadIdx.x < s) cnt[threadIdx.x] += cnt[threadIdx.x + s];
        __syncthreads();
    }
    if (threadIdx.x == 0) *flag = (cnt[0] * 8 < 8192) ? 1 : 0;
}

// ---------------------------------------------------------------------------
// Kernel 1: projections -> bf16 proj in MFMA-ready layouts.
//   Blocks 0..99   : theta+phi, thread per (sec,b,n), 16 ci outputs per pixel.
//   Blocks 100..124: gx+gbf, thread per (arr,b,n4), 16ci x 4keys outputs.
// ---------------------------------------------------------------------------
__global__ __launch_bounds__(256)
void proj_kernel(const void* __restrict__ bfimg, const void* __restrict__ x,
                 const void* __restrict__ w_theta, const void* __restrict__ b_theta,
                 const void* __restrict__ w_phi,   const void* __restrict__ b_phi,
                 const void* __restrict__ w_g,     const void* __restrict__ b_g,
                 const void* __restrict__ w_gbf,   const void* __restrict__ b_gbf,
                 const int* __restrict__ flagp,
                 char* __restrict__ th_p, char* __restrict__ ph_p,
                 char* __restrict__ gx_p, char* __restrict__ gb_p)
{
    const int bf = *flagp;
    if (blockIdx.x < 100) {
        // ---- theta / phi: one thread per pixel ----
        int idx = blockIdx.x * 256 + threadIdx.x;     // [0, 25600)
        int sec = idx / (kB * kN);                    // 0 = theta, 1 = phi
        int r   = idx % (kB * kN);
        int b   = r / kN;
        int n   = r % kN;
        const void* w    = sec ? w_phi : w_theta;
        const void* bias = sec ? b_phi : b_theta;

        float in[kC];
#pragma unroll 8
        for (int ch = 0; ch < kC; ++ch)
            in[ch] = ldin(bfimg, ((size_t)b * kC + ch) * kN + n, bf);

        unsigned short o[kCi];
#pragma unroll
        for (int ci = 0; ci < kCi; ++ci) {
            float acc = ldin(bias, ci, bf);
#pragma unroll 8
            for (int ch = 0; ch < kC; ++ch)
                acc = fmaf(ldin(w, (size_t)ci * kC + ch, bf), in[ch], acc);
            o[ci] = f2bf(acc);
        }
        uint4 lo, hi;
        lo.x = pack2(o[0], o[1]);  lo.y = pack2(o[2], o[3]);
        lo.z = pack2(o[4], o[5]);  lo.w = pack2(o[6], o[7]);
        hi.x = pack2(o[8], o[9]);  hi.y = pack2(o[10], o[11]);
        hi.z = pack2(o[12], o[13]); hi.w = pack2(o[14], o[15]);
        char* dst = sec ? (ph_p + ((size_t)b * kN + n) * PHB)
                        : (th_p + ((size_t)b * kN + n) * THB);
        *(uint4*)dst        = lo;
        *(uint4*)(dst + 16) = hi;
    } else {
        // ---- gx / gbf: one thread per 4-key group ----
        int idx = (blockIdx.x - 100) * 256 + threadIdx.x;  // [0, 6400)
        int arr = idx / (kB * (kN / 4));                   // 0 = gx(x), 1 = gbf(bfimg)
        int r   = idx % (kB * (kN / 4));
        int b   = r / (kN / 4);
        int n4  = r % (kN / 4);
        int n   = n4 * 4;
        const void* src  = arr ? bfimg : x;
        const void* w    = arr ? w_gbf : w_g;
        const void* bias = arr ? b_gbf : b_g;

        float acc[kCi][4];
#pragma unroll
        for (int ci = 0; ci < kCi; ++ci) {
            float bv = ldin(bias, ci, bf);
            acc[ci][0] = acc[ci][1] = acc[ci][2] = acc[ci][3] = bv;
        }
#pragma unroll 4
        for (int ch = 0; ch < kC; ++ch) {
            float v0, v1, v2, v3;
            size_t base = ((size_t)b * kC + ch) * kN + n;
            if (bf) {
                const unsigned short* sp = (const unsigned short*)src + base;
                ushort4 v = *(const ushort4*)sp;
                v0 = __uint_as_float((unsigned)v.x << 16);
                v1 = __uint_as_float((unsigned)v.y << 16);
                v2 = __uint_as_float((unsigned)v.z << 16);
                v3 = __uint_as_float((unsigned)v.w << 16);
            } else {
                float4 v = *(const float4*)((const float*)src + base);
                v0 = v.x; v1 = v.y; v2 = v.z; v3 = v.w;
            }
#pragma unroll
            for (int ci = 0; ci < kCi; ++ci) {
                float wv = ldin(w, (size_t)ci * kC + ch, bf);
                acc[ci][0] = fmaf(wv, v0, acc[ci][0]);
                acc[ci][1] = fmaf(wv, v1, acc[ci][1]);
                acc[ci][2] = fmaf(wv, v2, acc[ci][2]);
                acc[ci][3] = fmaf(wv, v3, acc[ci][3]);
            }
        }
        // pack [ci][4] -> 128 B contiguous
        char* dst = (arr ? gb_p : gx_p) + ((size_t)b * (kN / 4) + n4) * GRB;
        unsigned out[32];
#pragma unroll
        for (int ci = 0; ci < kCi; ++ci) {
            out[ci * 2 + 0] = pack2(f2bf(acc[ci][0]), f2bf(acc[ci][1]));
            out[ci * 2 + 1] = pack2(f2bf(acc[ci][2]), f2bf(acc[ci][3]));
        }
#pragma unroll
        for (int m = 0; m < 8; ++m) {
            uint4 v; v.x = out[m*4]; v.y = out[m*4+1]; v.z = out[m*4+2]; v.w = out[m*4+3];
            *(uint4*)(dst + m * 16) = v;
        }
    }
}

// ---------------------------------------------------------------------------
// Kernel 2: MFMA attention. Block = 16 queries, 4 waves; wave w owns keys
// [w*32, w*32+32) of each 128-key chunk (two 16x16x32 QK tiles + one PV step
// per branch). Double-buffered global_load_lds staging (1024 granules =
// exactly 4 DMA/thread/chunk). Softmax exact fp32, no max-sub.
//
// Layout notes (robust to A/B k-slot permutation; relies only on the
// HW-verified C/D mapping col=lane&15, row=(lane>>4)*4+r):
//  - QK^T computed swapped: A=phi(keys as rows), B=theta(queries as cols)
//    -> lane holds P[q=lane&15][keys 4g+r per tile]: exactly PV's A rows.
//  - A and B both place channel 8g+j at slot (g,j); zero channels (16..31)
//    occupy the same slots on both sides -> permutation-invariant dot.
//  - PV slot (g,j) carries key K(g,j) = j<4 ? T0:4g+j : T1:4g+j-4 on both
//    the P (A) side and the G (B) side.
// ---------------------------------------------------------------------------
__global__ __launch_bounds__(256, 4)
void attn_kernel(const char* __restrict__ th_p, const char* __restrict__ ph_p,
                 const char* __restrict__ gx_p, const char* __restrict__ gb_p,
                 const void* __restrict__ bfimg, const void* __restrict__ x,
                 const void* __restrict__ w_W,  const void* __restrict__ b_W,
                 const void* __restrict__ gamma, const void* __restrict__ beta,
                 const void* __restrict__ mean,  const void* __restrict__ var,
                 const int* __restrict__ flagp, void* __restrict__ out)
{
    __shared__ __align__(16) char smem[2 * BUF_BYTES + 512];  // 33280 B

    const int bf  = *flagp;
    const int tid = threadIdx.x;
    const int w   = tid >> 6;
    const int l   = tid & 63;
    const int g   = l >> 4;
    const int h   = l & 15;
    const int b   = blockIdx.x / (kN / QT);
    const int q0  = (blockIdx.x % (kN / QT)) * QT;

    // ---- DMA plan: granule G = R*256+tid; regions ph[0,384) gx[384,704) gb[704,1024) ----
    const char* src[4]; int str[4]; int dof[4];
#pragma unroll
    for (int R = 0; R < 4; ++R) {
        int G = R * 256 + tid;
        if (G < 384)      { src[R] = ph_p + (size_t)b * kN * PHB        + (size_t)G * 16;        str[R] = PH_BYTES; }
        else if (G < 704) { src[R] = gx_p + (size_t)b * (kN/4) * GRB    + (size_t)(G - 384) * 16; str[R] = G_BYTES; }
        else              { src[R] = gb_p + (size_t)b * (kN/4) * GRB    + (size_t)(G - 704) * 16; str[R] = G_BYTES; }
        dof[R] = G * 16;
    }
#define STAGE(it, sel)                                                          \
    {                                                                           \
        _Pragma("unroll")                                                       \
        for (int R = 0; R < 4; ++R)                                             \
            g2lds16(src[R] + (size_t)(it) * str[R],                             \
                    smem + (sel) * BUF_BYTES + dof[R]);                         \
    }

    // ---- prologue: chunk 0 + theta tile (rows q0..q0+15 = contiguous 512B) ----
    STAGE(0, 0);
    ((unsigned short*)(smem + 2 * BUF_BYTES))[tid & 255] =
        *(const unsigned short*)(th_p + ((size_t)b * kN + q0) * THB + tid * 2);
    __syncthreads();

    bf16x8 bq;
#pragma unroll
    for (int j = 0; j < 8; ++j) bq[j] = 0;
    if (g < 2) bq = *(const bf16x8*)(smem + 2 * BUF_BYTES + h * THB + g * 16);

    const f32x4 z4 = {0.f, 0.f, 0.f, 0.f};
    f32x4 accx = z4, accb = z4;
    float lsum = 0.f;

    for (int it = 0; it < NCH; ++it) {
        if (it + 1 < NCH) STAGE(it + 1, (it + 1) & 1);
        const char* buf = smem + (it & 1) * BUF_BYTES;

        // --- QK^T: A = phi rows (this wave's two 16-key tiles) ---
        bf16x8 a0, a1;
#pragma unroll
        for (int j = 0; j < 8; ++j) { a0[j] = 0; a1[j] = 0; }
        if (g < 2) {
            a0 = *(const bf16x8*)(buf + (w * 32 + h) * PHB + g * 16);
            a1 = *(const bf16x8*)(buf + (w * 32 + 16 + h) * PHB + g * 16);
        }
        f32x4 s0 = __builtin_amdgcn_mfma_f32_16x16x32_bf16(a0, bq, z4, 0, 0, 0);
        f32x4 s1 = __builtin_amdgcn_mfma_f32_16x16x32_bf16(a1, bq, z4, 0, 0, 0);

        // --- softmax numerators (exact, no max-sub) ---
        float p0 = __expf(s0[0]), p1 = __expf(s0[1]), p2 = __expf(s0[2]), p3 = __expf(s0[3]);
        float p4 = __expf(s1[0]), p5 = __expf(s1[1]), p6 = __expf(s1[2]), p7 = __expf(s1[3]);
        lsum += (p0 + p1) + (p2 + p3) + (p4 + p5) + (p6 + p7);

        union { unsigned short u[8]; bf16x8 v; } pa;
        pa.u[0] = f2bf(p0); pa.u[1] = f2bf(p1); pa.u[2] = f2bf(p2); pa.u[3] = f2bf(p3);
        pa.u[4] = f2bf(p4); pa.u[5] = f2bf(p5); pa.u[6] = f2bf(p6); pa.u[7] = f2bf(p7);

        // --- PV: B = G fragments, slot (g,j) <-> key K(g,j) ---
        const char* gxb = buf + PH_BYTES + h * 8;
        const char* gbb = buf + PH_BYTES + G_BYTES + h * 8;
        union { uint2 q[2]; bf16x8 v; } bx, bb;
        bx.q[0] = *(const uint2*)(gxb + (8 * w + g) * GRB);
        bx.q[1] = *(const uint2*)(gxb + (8 * w + 4 + g) * GRB);
        bb.q[0] = *(const uint2*)(gbb + (8 * w + g) * GRB);
        bb.q[1] = *(const uint2*)(gbb + (8 * w + 4 + g) * GRB);

        accx = __builtin_amdgcn_mfma_f32_16x16x32_bf16(pa.v, bx.v, accx, 0, 0, 0);
        accb = __builtin_amdgcn_mfma_f32_16x16x32_bf16(pa.v, bb.v, accb, 0, 0, 0);

        __syncthreads();   // next buffer DMA'd (vmcnt drain); all reads of cur done
    }
#undef STAGE

    // ---- reduce l across lane-groups: lanes 0-15 hold total for q=l ----
    lsum += __shfl_down(lsum, 16);
    lsum += __shfl_down(lsum, 32);

    // buffers dead after final barrier; reuse LDS
    float* ys = (float*)smem;            // [w][br][q][ci]  8192 B
    float* ls = (float*)(smem + 8192);   // [w][q]          256 B
    float* y2 = (float*)(smem + 8448);   // [q][33]         2112 B
    if (l < 16) ls[w * 16 + l] = lsum;
#pragma unroll
    for (int r = 0; r < 4; ++r) {
        int q = g * 4 + r;               // verified D layout: row=(lane>>4)*4+r
        ys[(((w * 2 + 0) * 16) + q) * 16 + h] = accx[r];
        ys[(((w * 2 + 1) * 16) + q) * 16 + h] = accb[r];
    }
    __syncthreads();

    // ---- cross-wave reduce + normalize ----
    for (int i = tid; i < 512; i += 256) {
        int ci = i & 15, q = (i >> 4) & 15, br = i >> 8;
        float v = ys[((0 + br) * 16 + q) * 16 + ci] + ys[((2 + br) * 16 + q) * 16 + ci]
                + ys[((4 + br) * 16 + q) * 16 + ci] + ys[((6 + br) * 16 + q) * 16 + ci];
        float lq = ls[q] + ls[16 + q] + ls[32 + q] + ls[48 + q];
        y2[q * 33 + br * 16 + ci] = v / lq;
    }
    __syncthreads();

    // ---- epilogue: z = BN(w_W . y + b_W) + residual, both branches ----
    const int q  = tid & 15;
    const int cb = tid >> 4;
#pragma unroll
    for (int i = 0; i < 8; ++i) {
        const int ch2 = cb * 8 + i;
        const int br  = ch2 >> 6;
        const int ch  = ch2 & 63;
        float wy = ldin(b_W, ch, bf);
#pragma unroll
        for (int ci = 0; ci < kCi; ++ci)
            wy = fmaf(ldin(w_W, (size_t)ch * kCi + ci, bf), y2[q * 33 + br * kCi + ci], wy);
        float inv = rsqrtf(ldin(var, ch, bf) + EPS_BN);
        float z = (wy - ldin(mean, ch, bf)) * (ldin(gamma, ch, bf) * inv) + ldin(beta, ch, bf);
        const void* res = br ? bfimg : x;
        z += ldin(res, ((size_t)b * kC + ch) * kN + q0 + q, bf);
        stout(out, ((size_t)b * 2 * kC + ch2) * kN + q0 + q, z, bf);
    }
}

// ---------------------------------------------------------------------------
extern "C" void kernel_launch(void* const* d_in, const int* in_sizes, int n_in,
                              void* d_out, int out_size, void* d_ws, size_t ws_size,
                              hipStream_t stream)
{
    const void* bfimg   = d_in[0];
    const void* x       = d_in[1];
    const void* w_theta = d_in[2];
    const void* b_theta = d_in[3];
    const void* w_phi   = d_in[4];
    const void* b_phi   = d_in[5];
    const void* w_g     = d_in[6];
    const void* b_g     = d_in[7];
    const void* w_gbf   = d_in[8];
    const void* b_gbf   = d_in[9];
    const void* w_W     = d_in[10];
    const void* b_W     = d_in[11];
    const void* gamma   = d_in[12];
    const void* beta    = d_in[13];
    const void* mean    = d_in[14];
    const void* var     = d_in[15];

    int*  flag = (int*)d_ws;
    char* base = (char*)d_ws;
    char* th_p = base + 256;                               // 2*6400*32 = 409600
    char* ph_p = th_p + (size_t)kB * kN * THB;             // 2*6400*48 = 614400
    char* gx_p = ph_p + (size_t)kB * kN * PHB;             // 2*1600*160 = 512000
    char* gb_p = gx_p + (size_t)kB * (kN / 4) * GRB;       // 512000  (total ~2.05 MB)

    detect_kernel<<<1, 256, 0, stream>>>(bfimg, flag);

    proj_kernel<<<125, 256, 0, stream>>>(
        bfimg, x, w_theta, b_theta, w_phi, b_phi, w_g, b_g, w_gbf, b_gbf,
        flag, th_p, ph_p, gx_p, gb_p);

    attn_kernel<<<kB * (kN / QT), 256, 0, stream>>>(
        th_p, ph_p, gx_p, gb_p,
        bfimg, x, w_W, b_W, gamma, beta, mean, var, flag, d_out);
}

// Round 4
// 143.981 us; speedup vs baseline: 4.3984x; 1.3968x over previous
//
#include <hip/hip_runtime.h>
#include <hip/hip_bf16.h>

typedef __hip_bfloat16 bf16;
typedef __attribute__((ext_vector_type(4))) float f32x4;
typedef __attribute__((ext_vector_type(8))) short bf16x8;

constexpr int kB  = 2;
constexpr int kC  = 64;
constexpr int kCi = 16;
constexpr int kN  = 6400;   // 80*80
constexpr int QT  = 16;     // queries per block
constexpr int KT  = 128;    // keys per chunk
constexpr int NCH = kN / KT; // 50

// proj scratch layouts (all bf16):
//   theta: [b][n][ci]              rows 32 B
//   phi:   [b][n][ci + 8B pad]     rows 48 B (pad unread; keeps b128 rows 16B-aligned, 2-way banks)
//   gx/gb: [b][n/4][ci][4keys]+pad groups 160 B (128 used)
constexpr int THB = 32;
constexpr int PHB = 48;
constexpr int GRB = 160;
constexpr int PH_BYTES  = KT * PHB;        // 6144
constexpr int G_BYTES   = (KT / 4) * GRB;  // 5120
constexpr int BUF_BYTES = PH_BYTES + 2 * G_BYTES; // 16384 (ph | gx | gb contiguous)

#define EPS_BN 1e-5f

__device__ __forceinline__ float b2f(bf16 v) { return __bfloat162float(v); }
__device__ __forceinline__ unsigned short f2bf(float f) {
    bf16 h = __float2bfloat16(f);
    return *reinterpret_cast<unsigned short*>(&h);
}
__device__ __forceinline__ float ldin(const void* p, size_t i, int bf) {
    return bf ? __bfloat162float(((const bf16*)p)[i]) : ((const float*)p)[i];
}
__device__ __forceinline__ void stout(void* p, size_t i, float v, int bf) {
    if (bf) ((bf16*)p)[i] = __float2bfloat16(v);
    else    ((float*)p)[i] = v;
}
__device__ __forceinline__ void g2lds16(const void* gsrc, void* ldst) {
    __builtin_amdgcn_global_load_lds(
        (const __attribute__((address_space(1))) void*)gsrc,
        (__attribute__((address_space(3))) void*)ldst,
        16, 0, 0);
}
__device__ __forceinline__ unsigned pack2(unsigned short a, unsigned short b) {
    return (unsigned)a | ((unsigned)b << 16);
}

// ---------------------------------------------------------------------------
// Kernel 0: dtype detector (unchanged).
// ---------------------------------------------------------------------------
__global__ __launch_bounds__(256)
void detect_kernel(const void* __restrict__ src, int* __restrict__ flag)
{
    __shared__ int cnt[256];
    const unsigned short* u = (const unsigned short*)src;
    int wild = 0;
    for (int i = threadIdx.x; i < 8192; i += 256) {
        int e = (u[i] >> 7) & 0xFF;
        if (e < 64 || e > 191) wild++;
    }
    cnt[threadIdx.x] = wild;
    __syncthreads();
    for (int s = 128; s > 0; s >>= 1) {
        if (threadIdx.x < s) cnt[threadIdx.x] += cnt[threadIdx.x + s];
        __syncthreads();
    }
    if (threadIdx.x == 0) *flag = (cnt[0] * 8 < 8192) ? 1 : 0;
}

// ---------------------------------------------------------------------------
// Kernel 1 (v2): projections -> bf16 in MFMA-ready layouts.
// Grid = 800 blocks; block = (sec, b, 64-pixel tile). sec: 0=theta 1=phi
// 2=gx(x) 3=gbf(bfimg). Weights staged in LDS (fp32); thread (px, ci-quad)
// does 64 coalesced channel loads x 4 FMA; outputs assembled in LDS in the
// final bf16 layout and stored as coalesced uint4s.
// ---------------------------------------------------------------------------
__global__ __launch_bounds__(256)
void proj_kernel(const void* __restrict__ bfimg, const void* __restrict__ x,
                 const void* __restrict__ w_theta, const void* __restrict__ b_theta,
                 const void* __restrict__ w_phi,   const void* __restrict__ b_phi,
                 const void* __restrict__ w_g,     const void* __restrict__ b_g,
                 const void* __restrict__ w_gbf,   const void* __restrict__ b_gbf,
                 const int* __restrict__ flagp,
                 char* __restrict__ th_p, char* __restrict__ ph_p,
                 char* __restrict__ gx_p, char* __restrict__ gb_p)
{
    __shared__ float w_s[kCi][kC];                 // 4 KB
    __shared__ float b_s[kCi];
    __shared__ __align__(16) char out_s[64 * PHB]; // 3072 B (max of 2048/3072/2560)

    const int bf  = *flagp;
    const int tid = threadIdx.x;
    const int bid = blockIdx.x;        // [0, 800)
    const int sec = bid / 200;         // 0..3
    const int r   = bid % 200;
    const int b   = r / 100;
    const int t64 = r % 100;
    const int n0  = t64 * 64;

    const void *src, *w, *bias;
    if (sec == 0)      { src = bfimg; w = w_theta; bias = b_theta; }
    else if (sec == 1) { src = bfimg; w = w_phi;   bias = b_phi;   }
    else if (sec == 2) { src = x;     w = w_g;     bias = b_g;     }
    else               { src = bfimg; w = w_gbf;   bias = b_gbf;   }

    for (int i = tid; i < kCi * kC; i += 256)
        w_s[i >> 6][i & 63] = ldin(w, i, bf);
    if (tid < kCi) b_s[tid] = ldin(bias, tid, bf);
    __syncthreads();

    const int px = tid & 63;
    const int cg = tid >> 6;           // ci quad: cg*4 .. cg*4+3
    const int n  = n0 + px;

    float a0 = b_s[cg * 4 + 0], a1 = b_s[cg * 4 + 1];
    float a2 = b_s[cg * 4 + 2], a3 = b_s[cg * 4 + 3];
    const size_t ibase = (size_t)b * kC * kN + n;
#pragma unroll 8
    for (int ch = 0; ch < kC; ++ch) {
        float v = ldin(src, ibase + (size_t)ch * kN, bf);
        a0 = fmaf(w_s[cg * 4 + 0][ch], v, a0);
        a1 = fmaf(w_s[cg * 4 + 1][ch], v, a1);
        a2 = fmaf(w_s[cg * 4 + 2][ch], v, a2);
        a3 = fmaf(w_s[cg * 4 + 3][ch], v, a3);
    }

    if (sec < 2) {
        // rows: [px][ci], 8 B per thread at px*RB + cg*8
        const int RB = sec ? PHB : THB;
        uint2 v; v.x = pack2(f2bf(a0), f2bf(a1)); v.y = pack2(f2bf(a2), f2bf(a3));
        *(uint2*)(out_s + px * RB + cg * 8) = v;
        __syncthreads();
        const int bytes = 64 * RB;                 // 2048 or 3072
        char* dst = (sec ? ph_p : th_p) + ((size_t)b * kN + n0) * RB;
        for (int i = tid * 16; i < bytes; i += 256 * 16)
            *(uint4*)(dst + i) = *(const uint4*)(out_s + i);
    } else {
        // g groups: group = px>>2, key k = px&3; halfword at ci*8 + k*2
        const int grp = px >> 2, k = px & 3;
        unsigned short* gbase = (unsigned short*)(out_s + grp * GRB);
        gbase[(cg * 4 + 0) * 4 + k] = f2bf(a0);
        gbase[(cg * 4 + 1) * 4 + k] = f2bf(a1);
        gbase[(cg * 4 + 2) * 4 + k] = f2bf(a2);
        gbase[(cg * 4 + 3) * 4 + k] = f2bf(a3);
        __syncthreads();
        const int bytes = 16 * GRB;                // 2560 (pad bytes garbage, unread)
        char* dst = (sec == 2 ? gx_p : gb_p) + ((size_t)b * (kN / 4) + (n0 >> 2)) * GRB;
        for (int i = tid * 16; i < bytes; i += 256 * 16)
            *(uint4*)(dst + i) = *(const uint4*)(out_s + i);
    }
}

// ---------------------------------------------------------------------------
// Kernel 2: MFMA attention (unchanged from round 3).
// ---------------------------------------------------------------------------
__global__ __launch_bounds__(256, 4)
void attn_kernel(const char* __restrict__ th_p, const char* __restrict__ ph_p,
                 const char* __restrict__ gx_p, const char* __restrict__ gb_p,
                 const void* __restrict__ bfimg, const void* __restrict__ x,
                 const void* __restrict__ w_W,  const void* __restrict__ b_W,
                 const void* __restrict__ gamma, const void* __restrict__ beta,
                 const void* __restrict__ mean,  const void* __restrict__ var,
                 const int* __restrict__ flagp, void* __restrict__ out)
{
    __shared__ __align__(16) char smem[2 * BUF_BYTES + 512];  // 33280 B

    const int bf  = *flagp;
    const int tid = threadIdx.x;
    const int w   = tid >> 6;
    const int l   = tid & 63;
    const int g   = l >> 4;
    const int h   = l & 15;
    const int b   = blockIdx.x / (kN / QT);
    const int q0  = (blockIdx.x % (kN / QT)) * QT;

    // ---- DMA plan: granule G = R*256+tid; regions ph[0,384) gx[384,704) gb[704,1024) ----
    const char* src[4]; int str[4]; int dof[4];
#pragma unroll
    for (int R = 0; R < 4; ++R) {
        int G = R * 256 + tid;
        if (G < 384)      { src[R] = ph_p + (size_t)b * kN * PHB        + (size_t)G * 16;        str[R] = PH_BYTES; }
        else if (G < 704) { src[R] = gx_p + (size_t)b * (kN/4) * GRB    + (size_t)(G - 384) * 16; str[R] = G_BYTES; }
        else              { src[R] = gb_p + (size_t)b * (kN/4) * GRB    + (size_t)(G - 704) * 16; str[R] = G_BYTES; }
        dof[R] = G * 16;
    }
#define STAGE(it, sel)                                                          \
    {                                                                           \
        _Pragma("unroll")                                                       \
        for (int R = 0; R < 4; ++R)                                             \
            g2lds16(src[R] + (size_t)(it) * str[R],                             \
                    smem + (sel) * BUF_BYTES + dof[R]);                         \
    }

    // ---- prologue: chunk 0 + theta tile (rows q0..q0+15 = contiguous 512B) ----
    STAGE(0, 0);
    ((unsigned short*)(smem + 2 * BUF_BYTES))[tid & 255] =
        *(const unsigned short*)(th_p + ((size_t)b * kN + q0) * THB + tid * 2);
    __syncthreads();

    bf16x8 bq;
#pragma unroll
    for (int j = 0; j < 8; ++j) bq[j] = 0;
    if (g < 2) bq = *(const bf16x8*)(smem + 2 * BUF_BYTES + h * THB + g * 16);

    const f32x4 z4 = {0.f, 0.f, 0.f, 0.f};
    f32x4 accx = z4, accb = z4;
    float lsum = 0.f;

    for (int it = 0; it < NCH; ++it) {
        if (it + 1 < NCH) STAGE(it + 1, (it + 1) & 1);
        const char* buf = smem + (it & 1) * BUF_BYTES;

        // --- QK^T: A = phi rows (this wave's two 16-key tiles) ---
        bf16x8 a0, a1;
#pragma unroll
        for (int j = 0; j < 8; ++j) { a0[j] = 0; a1[j] = 0; }
        if (g < 2) {
            a0 = *(const bf16x8*)(buf + (w * 32 + h) * PHB + g * 16);
            a1 = *(const bf16x8*)(buf + (w * 32 + 16 + h) * PHB + g * 16);
        }
        f32x4 s0 = __builtin_amdgcn_mfma_f32_16x16x32_bf16(a0, bq, z4, 0, 0, 0);
        f32x4 s1 = __builtin_amdgcn_mfma_f32_16x16x32_bf16(a1, bq, z4, 0, 0, 0);

        // --- softmax numerators (exact, no max-sub) ---
        float p0 = __expf(s0[0]), p1 = __expf(s0[1]), p2 = __expf(s0[2]), p3 = __expf(s0[3]);
        float p4 = __expf(s1[0]), p5 = __expf(s1[1]), p6 = __expf(s1[2]), p7 = __expf(s1[3]);
        lsum += (p0 + p1) + (p2 + p3) + (p4 + p5) + (p6 + p7);

        union { unsigned short u[8]; bf16x8 v; } pa;
        pa.u[0] = f2bf(p0); pa.u[1] = f2bf(p1); pa.u[2] = f2bf(p2); pa.u[3] = f2bf(p3);
        pa.u[4] = f2bf(p4); pa.u[5] = f2bf(p5); pa.u[6] = f2bf(p6); pa.u[7] = f2bf(p7);

        // --- PV: B = G fragments, slot (g,j) <-> key K(g,j) ---
        const char* gxb = buf + PH_BYTES + h * 8;
        const char* gbb = buf + PH_BYTES + G_BYTES + h * 8;
        union { uint2 q[2]; bf16x8 v; } bx, bb;
        bx.q[0] = *(const uint2*)(gxb + (8 * w + g) * GRB);
        bx.q[1] = *(const uint2*)(gxb + (8 * w + 4 + g) * GRB);
        bb.q[0] = *(const uint2*)(gbb + (8 * w + g) * GRB);
        bb.q[1] = *(const uint2*)(gbb + (8 * w + 4 + g) * GRB);

        accx = __builtin_amdgcn_mfma_f32_16x16x32_bf16(pa.v, bx.v, accx, 0, 0, 0);
        accb = __builtin_amdgcn_mfma_f32_16x16x32_bf16(pa.v, bb.v, accb, 0, 0, 0);

        __syncthreads();   // next buffer DMA'd (vmcnt drain); all reads of cur done
    }
#undef STAGE

    // ---- reduce l across lane-groups: lanes 0-15 hold total for q=l ----
    lsum += __shfl_down(lsum, 16);
    lsum += __shfl_down(lsum, 32);

    // buffers dead after final barrier; reuse LDS
    float* ys = (float*)smem;            // [w][br][q][ci]  8192 B
    float* ls = (float*)(smem + 8192);   // [w][q]          256 B
    float* y2 = (float*)(smem + 8448);   // [q][33]         2112 B
    if (l < 16) ls[w * 16 + l] = lsum;
#pragma unroll
    for (int r = 0; r < 4; ++r) {
        int q = g * 4 + r;               // verified D layout: row=(lane>>4)*4+r
        ys[(((w * 2 + 0) * 16) + q) * 16 + h] = accx[r];
        ys[(((w * 2 + 1) * 16) + q) * 16 + h] = accb[r];
    }
    __syncthreads();

    // ---- cross-wave reduce + normalize ----
    for (int i = tid; i < 512; i += 256) {
        int ci = i & 15, q = (i >> 4) & 15, br = i >> 8;
        float v = ys[((0 + br) * 16 + q) * 16 + ci] + ys[((2 + br) * 16 + q) * 16 + ci]
                + ys[((4 + br) * 16 + q) * 16 + ci] + ys[((6 + br) * 16 + q) * 16 + ci];
        float lq = ls[q] + ls[16 + q] + ls[32 + q] + ls[48 + q];
        y2[q * 33 + br * 16 + ci] = v / lq;
    }
    __syncthreads();

    // ---- epilogue: z = BN(w_W . y + b_W) + residual, both branches ----
    const int q  = tid & 15;
    const int cb = tid >> 4;
#pragma unroll
    for (int i = 0; i < 8; ++i) {
        const int ch2 = cb * 8 + i;
        const int br  = ch2 >> 6;
        const int ch  = ch2 & 63;
        float wy = ldin(b_W, ch, bf);
#pragma unroll
        for (int ci = 0; ci < kCi; ++ci)
            wy = fmaf(ldin(w_W, (size_t)ch * kCi + ci, bf), y2[q * 33 + br * kCi + ci], wy);
        float inv = rsqrtf(ldin(var, ch, bf) + EPS_BN);
        float z = (wy - ldin(mean, ch, bf)) * (ldin(gamma, ch, bf) * inv) + ldin(beta, ch, bf);
        const void* res = br ? bfimg : x;
        z += ldin(res, ((size_t)b * kC + ch) * kN + q0 + q, bf);
        stout(out, ((size_t)b * 2 * kC + ch2) * kN + q0 + q, z, bf);
    }
}

// ---------------------------------------------------------------------------
extern "C" void kernel_launch(void* const* d_in, const int* in_sizes, int n_in,
                              void* d_out, int out_size, void* d_ws, size_t ws_size,
                              hipStream_t stream)
{
    const void* bfimg   = d_in[0];
    const void* x       = d_in[1];
    const void* w_theta = d_in[2];
    const void* b_theta = d_in[3];
    const void* w_phi   = d_in[4];
    const void* b_phi   = d_in[5];
    const void* w_g     = d_in[6];
    const void* b_g     = d_in[7];
    const void* w_gbf   = d_in[8];
    const void* b_gbf   = d_in[9];
    const void* w_W     = d_in[10];
    const void* b_W     = d_in[11];
    const void* gamma   = d_in[12];
    const void* beta    = d_in[13];
    const void* mean    = d_in[14];
    const void* var     = d_in[15];

    int*  flag = (int*)d_ws;
    char* base = (char*)d_ws;
    char* th_p = base + 256;                               // 2*6400*32 = 409600
    char* ph_p = th_p + (size_t)kB * kN * THB;             // 2*6400*48 = 614400
    char* gx_p = ph_p + (size_t)kB * kN * PHB;             // 2*1600*160 = 512000
    char* gb_p = gx_p + (size_t)kB * (kN / 4) * GRB;       // 512000  (total ~2.05 MB)

    detect_kernel<<<1, 256, 0, stream>>>(bfimg, flag);

    proj_kernel<<<800, 256, 0, stream>>>(
        bfimg, x, w_theta, b_theta, w_phi, b_phi, w_g, b_g, w_gbf, b_gbf,
        flag, th_p, ph_p, gx_p, gb_p);

    attn_kernel<<<kB * (kN / QT), 256, 0, stream>>>(
        th_p, ph_p, gx_p, gb_p,
        bfimg, x, w_W, b_W, gamma, beta, mean, var, flag, d_out);
}

// Round 9
// 136.224 us; speedup vs baseline: 4.6488x; 1.0569x over previous
//
#include <hip/hip_runtime.h>
#include <hip/hip_bf16.h>

typedef __hip_bfloat16 bf16;
typedef __attribute__((ext_vector_type(4))) float f32x4;
typedef __attribute__((ext_vector_type(8))) short bf16x8;

constexpr int kB  = 2;
constexpr int kC  = 64;
constexpr int kCi = 16;
constexpr int kN  = 6400;   // 80*80
constexpr int QT  = 16;     // queries per block
constexpr int KT  = 128;    // keys per chunk
constexpr int NCH = kN / KT; // 50

// proj scratch layouts (all bf16):
//   theta: [b][n][ci]              rows 32 B
//   phi:   [b][n][ci + 8B pad]     rows 48 B (pad unread)
//   gx/gb: [b][n/4][ci][4keys]+pad groups 160 B (128 used)
constexpr int THB = 32;
constexpr int PHB = 48;
constexpr int GRB = 160;
constexpr int PH_BYTES  = KT * PHB;        // 6144
constexpr int G_BYTES   = (KT / 4) * GRB;  // 5120
constexpr int BUF_BYTES = PH_BYTES + 2 * G_BYTES; // 16384
// per-wave slice inside a buffer: ph 1536 | gx 1280 | gb 1280 = 4096 B
constexpr int WSL = 4096;
constexpr int W_PH = 1536;
constexpr int W_GX = 1280;

#define EPS_BN 1e-5f

__device__ __forceinline__ float b2f(bf16 v) { return __bfloat162float(v); }
__device__ __forceinline__ unsigned short f2bf(float f) {
    bf16 h = __float2bfloat16(f);
    return *reinterpret_cast<unsigned short*>(&h);
}
__device__ __forceinline__ float ldin(const void* p, size_t i, int bf) {
    return bf ? __bfloat162float(((const bf16*)p)[i]) : ((const float*)p)[i];
}
__device__ __forceinline__ void stout(void* p, size_t i, float v, int bf) {
    if (bf) ((bf16*)p)[i] = __float2bfloat16(v);
    else    ((float*)p)[i] = v;
}
__device__ __forceinline__ void g2lds16(const void* gsrc, void* ldst) {
    __builtin_amdgcn_global_load_lds(
        (const __attribute__((address_space(1))) void*)gsrc,
        (__attribute__((address_space(3))) void*)ldst,
        16, 0, 0);
}
__device__ __forceinline__ unsigned pack2(unsigned short a, unsigned short b) {
    return (unsigned)a | ((unsigned)b << 16);
}
// count "wild" bf16 exponents (e<64 || e>191) in 8 halfwords of a uint4
__device__ __forceinline__ int wild8(uint4 v) {
    int wc = 0;
    unsigned u[4] = {v.x, v.y, v.z, v.w};
#pragma unroll
    for (int i = 0; i < 4; ++i) {
        int e0 = (u[i] >> 7)  & 0xFF;
        int e1 = (u[i] >> 23) & 0xFF;
        wc += (e0 < 64 || e0 > 191);
        wc += (e1 < 64 || e1 > 191);
    }
    return wc;
}

// ---------------------------------------------------------------------------
// Kernel 1: projections -> bf16 in MFMA-ready layouts. Self-detects dtype
// (2048-halfword sample of bfimg, block-local reduction).
// Grid = 800 blocks; block = (sec, b, 64-pixel tile).
// ---------------------------------------------------------------------------
__global__ __launch_bounds__(256)
void proj_kernel(const void* __restrict__ bfimg, const void* __restrict__ x,
                 const void* __restrict__ w_theta, const void* __restrict__ b_theta,
                 const void* __restrict__ w_phi,   const void* __restrict__ b_phi,
                 const void* __restrict__ w_g,     const void* __restrict__ b_g,
                 const void* __restrict__ w_gbf,   const void* __restrict__ b_gbf,
                 char* __restrict__ th_p, char* __restrict__ ph_p,
                 char* __restrict__ gx_p, char* __restrict__ gb_p)
{
    __shared__ float w_s[kCi][kC];                 // 4 KB
    __shared__ float b_s[kCi];
    __shared__ __align__(16) char out_s[64 * PHB]; // 3072 B
    __shared__ int dred[4];

    const int tid = threadIdx.x;
    const int wv  = tid >> 6;
    const int l   = tid & 63;

    // ---- dtype self-detect ----
    int wc = wild8(*(const uint4*)((const char*)bfimg + tid * 16));
#pragma unroll
    for (int off = 32; off > 0; off >>= 1) wc += __shfl_down(wc, off);
    if (l == 0) dred[wv] = wc;
    __syncthreads();
    const int bf = ((dred[0] + dred[1] + dred[2] + dred[3]) * 8 < 2048) ? 1 : 0;

    const int bid = blockIdx.x;        // [0, 800)
    const int sec = bid / 200;         // 0..3
    const int r   = bid % 200;
    const int b   = r / 100;
    const int t64 = r % 100;
    const int n0  = t64 * 64;

    const void *src, *w, *bias;
    if (sec == 0)      { src = bfimg; w = w_theta; bias = b_theta; }
    else if (sec == 1) { src = bfimg; w = w_phi;   bias = b_phi;   }
    else if (sec == 2) { src = x;     w = w_g;     bias = b_g;     }
    else               { src = bfimg; w = w_gbf;   bias = b_gbf;   }

    for (int i = tid; i < kCi * kC; i += 256)
        w_s[i >> 6][i & 63] = ldin(w, i, bf);
    if (tid < kCi) b_s[tid] = ldin(bias, tid, bf);
    __syncthreads();

    const int px = tid & 63;
    const int cg = tid >> 6;           // ci quad
    const int n  = n0 + px;

    float a0 = b_s[cg * 4 + 0], a1 = b_s[cg * 4 + 1];
    float a2 = b_s[cg * 4 + 2], a3 = b_s[cg * 4 + 3];
    const size_t ibase = (size_t)b * kC * kN + n;
#pragma unroll 8
    for (int ch = 0; ch < kC; ++ch) {
        float v = ldin(src, ibase + (size_t)ch * kN, bf);
        a0 = fmaf(w_s[cg * 4 + 0][ch], v, a0);
        a1 = fmaf(w_s[cg * 4 + 1][ch], v, a1);
        a2 = fmaf(w_s[cg * 4 + 2][ch], v, a2);
        a3 = fmaf(w_s[cg * 4 + 3][ch], v, a3);
    }

    if (sec < 2) {
        const int RB = sec ? PHB : THB;
        uint2 v; v.x = pack2(f2bf(a0), f2bf(a1)); v.y = pack2(f2bf(a2), f2bf(a3));
        *(uint2*)(out_s + px * RB + cg * 8) = v;
        __syncthreads();
        const int bytes = 64 * RB;
        char* dst = (sec ? ph_p : th_p) + ((size_t)b * kN + n0) * RB;
        for (int i = tid * 16; i < bytes; i += 256 * 16)
            *(uint4*)(dst + i) = *(const uint4*)(out_s + i);
    } else {
        const int grp = px >> 2, k = px & 3;
        unsigned short* gbase = (unsigned short*)(out_s + grp * GRB);
        gbase[(cg * 4 + 0) * 4 + k] = f2bf(a0);
        gbase[(cg * 4 + 1) * 4 + k] = f2bf(a1);
        gbase[(cg * 4 + 2) * 4 + k] = f2bf(a2);
        gbase[(cg * 4 + 3) * 4 + k] = f2bf(a3);
        __syncthreads();
        const int bytes = 16 * GRB;
        char* dst = (sec == 2 ? gx_p : gb_p) + ((size_t)b * (kN / 4) + (n0 >> 2)) * GRB;
        for (int i = tid * 16; i < bytes; i += 256 * 16)
            *(uint4*)(dst + i) = *(const uint4*)(out_s + i);
    }
}

// ---------------------------------------------------------------------------
// Kernel 2: MFMA attention, barrier-free main loop.
// Wave-private staging: wave w stages and reads ONLY its 32-key slice
// (ph 1536 B | gx 1280 B | gb 1280 B = 4 KB per wave per buffer); per-chunk
// sync is a per-wave counted s_waitcnt vmcnt(4) (FIFO vmcnt retire =>
// stage(it) complete when only stage(it+1)'s 4 DMAs remain), no block
// barrier. Waves drift freely; DMA latency hides under other waves' compute.
//
// ROUND-6 BUG FIX: the post-loop LDS reuse (ys/ls) aliases other waves'
// still-live buffer slices; with waves drifting, a fast wave's ys writes
// clobbered a slow wave's phi data -> NaN. One __syncthreads() now fences
// loop-exit before any reuse write. (1 barrier/block instead of 50.)
// ---------------------------------------------------------------------------
__global__ __launch_bounds__(256, 4)
void attn_kernel(const char* __restrict__ th_p, const char* __restrict__ ph_p,
                 const char* __restrict__ gx_p, const char* __restrict__ gb_p,
                 const void* __restrict__ bfimg, const void* __restrict__ x,
                 const void* __restrict__ w_W,  const void* __restrict__ b_W,
                 const void* __restrict__ gamma, const void* __restrict__ beta,
                 const void* __restrict__ mean,  const void* __restrict__ var,
                 void* __restrict__ out)
{
    __shared__ __align__(16) char smem[2 * BUF_BYTES + 512];  // 33280 B

    const int tid = threadIdx.x;
    const int w   = tid >> 6;
    const int l   = tid & 63;
    const int g   = l >> 4;
    const int h   = l & 15;
    const int b   = blockIdx.x / (kN / QT);
    const int q0  = (blockIdx.x % (kN / QT)) * QT;

    // ---- dtype self-detect sample (reduced after main loop) ----
    int wc = wild8(*(const uint4*)((const char*)bfimg + tid * 16));

    // ---- wave-private DMA plan: instr R, lane l -> wave-slice byte
    //      ofs = (R*64+l)*16; LDS dst = w*WSL + ofs (uniform base + l*16) ----
    const char* srcp[4]; int strv[4]; int dofs[4];
#pragma unroll
    for (int R = 0; R < 4; ++R) {
        int ofs = (R * 64 + l) * 16;
        if (ofs < W_PH) {
            srcp[R] = ph_p + (size_t)b * kN * PHB + (size_t)w * W_PH + ofs;
            strv[R] = PH_BYTES;
        } else if (ofs < W_PH + W_GX) {
            srcp[R] = gx_p + (size_t)b * (kN / 4) * GRB + (size_t)w * W_GX + (ofs - W_PH);
            strv[R] = G_BYTES;
        } else {
            srcp[R] = gb_p + (size_t)b * (kN / 4) * GRB + (size_t)w * W_GX + (ofs - W_PH - W_GX);
            strv[R] = G_BYTES;
        }
        dofs[R] = w * WSL + ofs;
    }
#define STAGE(it, sel)                                                      \
    {                                                                       \
        _Pragma("unroll")                                                   \
        for (int R = 0; R < 4; ++R)                                         \
            g2lds16(srcp[R] + (size_t)(it) * strv[R],                       \
                    smem + (sel) * BUF_BYTES + dofs[R]);                    \
    }

    // ---- prologue: chunk 0 + theta tile ----
    STAGE(0, 0);
    ((unsigned short*)(smem + 2 * BUF_BYTES))[tid] =
        *(const unsigned short*)(th_p + ((size_t)b * kN + q0) * THB + tid * 2);
    __syncthreads();                      // theta visible (also drains stage 0)

    bf16x8 bq;
#pragma unroll
    for (int j = 0; j < 8; ++j) bq[j] = 0;
    if (g < 2) bq = *(const bf16x8*)(smem + 2 * BUF_BYTES + h * THB + g * 16);

    const f32x4 z4 = {0.f, 0.f, 0.f, 0.f};
    f32x4 accx = z4, accb = z4;
    float lsum = 0.f;

    auto compute = [&](int it) {
        const char* wbuf = smem + (it & 1) * BUF_BYTES + w * WSL;

        // --- QK^T: A = phi rows (wave's two 16-key tiles) ---
        bf16x8 a0, a1;
#pragma unroll
        for (int j = 0; j < 8; ++j) { a0[j] = 0; a1[j] = 0; }
        if (g < 2) {
            a0 = *(const bf16x8*)(wbuf + h * PHB + g * 16);
            a1 = *(const bf16x8*)(wbuf + (16 + h) * PHB + g * 16);
        }
        f32x4 s0 = __builtin_amdgcn_mfma_f32_16x16x32_bf16(a0, bq, z4, 0, 0, 0);
        f32x4 s1 = __builtin_amdgcn_mfma_f32_16x16x32_bf16(a1, bq, z4, 0, 0, 0);

        // --- softmax numerators (exact, no max-sub) ---
        float p0 = __expf(s0[0]), p1 = __expf(s0[1]), p2 = __expf(s0[2]), p3 = __expf(s0[3]);
        float p4 = __expf(s1[0]), p5 = __expf(s1[1]), p6 = __expf(s1[2]), p7 = __expf(s1[3]);
        lsum += (p0 + p1) + (p2 + p3) + (p4 + p5) + (p6 + p7);

        union { unsigned short u[8]; bf16x8 v; } pa;
        pa.u[0] = f2bf(p0); pa.u[1] = f2bf(p1); pa.u[2] = f2bf(p2); pa.u[3] = f2bf(p3);
        pa.u[4] = f2bf(p4); pa.u[5] = f2bf(p5); pa.u[6] = f2bf(p6); pa.u[7] = f2bf(p7);

        // --- PV: B = G fragments (wave-local groups) ---
        const char* gxb = wbuf + W_PH + h * 8;
        const char* gbb = wbuf + W_PH + W_GX + h * 8;
        union { uint2 q[2]; bf16x8 v; } bx, bb;
        bx.q[0] = *(const uint2*)(gxb + g * GRB);
        bx.q[1] = *(const uint2*)(gxb + (4 + g) * GRB);
        bb.q[0] = *(const uint2*)(gbb + g * GRB);
        bb.q[1] = *(const uint2*)(gbb + (4 + g) * GRB);

        accx = __builtin_amdgcn_mfma_f32_16x16x32_bf16(pa.v, bx.v, accx, 0, 0, 0);
        accb = __builtin_amdgcn_mfma_f32_16x16x32_bf16(pa.v, bb.v, accb, 0, 0, 0);
    };

    // ---- barrier-free main loop: counted vmcnt, wave-private slices ----
    for (int it = 0; it < NCH - 1; ++it) {
        STAGE(it + 1, (it + 1) & 1);
        asm volatile("s_waitcnt vmcnt(4)" ::: "memory");   // stage(it) done
        __builtin_amdgcn_sched_barrier(0);
        compute(it);
    }
    asm volatile("s_waitcnt vmcnt(0)" ::: "memory");       // last chunk done
    __builtin_amdgcn_sched_barrier(0);
    compute(NCH - 1);
#undef STAGE

    // ---- reduce l across lane-groups: lanes 0-15 hold total for q=l ----
    lsum += __shfl_down(lsum, 16);
    lsum += __shfl_down(lsum, 32);
#pragma unroll
    for (int off = 32; off > 0; off >>= 1) wc += __shfl_down(wc, off);

    // FENCE before LDS reuse: all waves must be past their last buffer reads
    // before anyone overwrites smem (round-6 NaN race).
    __syncthreads();

    // buffers dead; reuse LDS
    float* ys = (float*)smem;            // [w][br][q][ci]  8192 B
    float* ls = (float*)(smem + 8192);   // [w][q]          256 B
    float* y2 = (float*)(smem + 8448);   // [q][33]         2112 B
    int*   wd = (int*)(smem + 10560);    // [w]             16 B
    if (l < 16) ls[w * 16 + l] = lsum;
    if (l == 0) wd[w] = wc;
#pragma unroll
    for (int r = 0; r < 4; ++r) {
        int q = g * 4 + r;               // verified D layout: row=(lane>>4)*4+r
        ys[(((w * 2 + 0) * 16) + q) * 16 + h] = accx[r];
        ys[(((w * 2 + 1) * 16) + q) * 16 + h] = accb[r];
    }
    __syncthreads();

    const int bf = ((wd[0] + wd[1] + wd[2] + wd[3]) * 8 < 2048) ? 1 : 0;

    // ---- cross-wave reduce + normalize ----
    for (int i = tid; i < 512; i += 256) {
        int ci = i & 15, q = (i >> 4) & 15, br = i >> 8;
        float v = ys[((0 + br) * 16 + q) * 16 + ci] + ys[((2 + br) * 16 + q) * 16 + ci]
                + ys[((4 + br) * 16 + q) * 16 + ci] + ys[((6 + br) * 16 + q) * 16 + ci];
        float lq = ls[q] + ls[16 + q] + ls[32 + q] + ls[48 + q];
        y2[q * 33 + br * 16 + ci] = v / lq;
    }
    __syncthreads();

    // ---- epilogue: z = BN(w_W . y + b_W) + residual, both branches ----
    const int q  = tid & 15;
    const int cb = tid >> 4;
#pragma unroll
    for (int i = 0; i < 8; ++i) {
        const int ch2 = cb * 8 + i;
        const int br  = ch2 >> 6;
        const int ch  = ch2 & 63;
        float wy = ldin(b_W, ch, bf);
#pragma unroll
        for (int ci = 0; ci < kCi; ++ci)
            wy = fmaf(ldin(w_W, (size_t)ch * kCi + ci, bf), y2[q * 33 + br * kCi + ci], wy);
        float inv = rsqrtf(ldin(var, ch, bf) + EPS_BN);
        float z = (wy - ldin(mean, ch, bf)) * (ldin(gamma, ch, bf) * inv) + ldin(beta, ch, bf);
        const void* res = br ? bfimg : x;
        z += ldin(res, ((size_t)b * kC + ch) * kN + q0 + q, bf);
        stout(out, ((size_t)b * 2 * kC + ch2) * kN + q0 + q, z, bf);
    }
}

// ---------------------------------------------------------------------------
extern "C" void kernel_launch(void* const* d_in, const int* in_sizes, int n_in,
                              void* d_out, int out_size, void* d_ws, size_t ws_size,
                              hipStream_t stream)
{
    const void* bfimg   = d_in[0];
    const void* x       = d_in[1];
    const void* w_theta = d_in[2];
    const void* b_theta = d_in[3];
    const void* w_phi   = d_in[4];
    const void* b_phi   = d_in[5];
    const void* w_g     = d_in[6];
    const void* b_g     = d_in[7];
    const void* w_gbf   = d_in[8];
    const void* b_gbf   = d_in[9];
    const void* w_W     = d_in[10];
    const void* b_W     = d_in[11];
    const void* gamma   = d_in[12];
    const void* beta    = d_in[13];
    const void* mean    = d_in[14];
    const void* var     = d_in[15];

    char* base = (char*)d_ws;
    char* th_p = base + 256;                               // 2*6400*32 = 409600
    char* ph_p = th_p + (size_t)kB * kN * THB;             // 2*6400*48 = 614400
    char* gx_p = ph_p + (size_t)kB * kN * PHB;             // 2*1600*160 = 512000
    char* gb_p = gx_p + (size_t)kB * (kN / 4) * GRB;       // 512000

    proj_kernel<<<800, 256, 0, stream>>>(
        bfimg, x, w_theta, b_theta, w_phi, b_phi, w_g, b_g, w_gbf, b_gbf,
        th_p, ph_p, gx_p, gb_p);

    attn_kernel<<<kB * (kN / QT), 256, 0, stream>>>(
        th_p, ph_p, gx_p, gb_p,
        bfimg, x, w_W, b_W, gamma, beta, mean, var, d_out);
}